// Round 15
// baseline (921.520 us; speedup 1.0000x reference)
//
#include <hip/hip_runtime.h>

#define RG_ITERS 12
#define RG_S 64
#define RG_IN 128
#define RG_H 16
#define RG_OUT 8
#define RG_BN_EPS 1e-5
#define RG_IN_THRESH 2e-3f   // f32 screen gap threshold, input layer (err bound ~1e-5)
#define RG_IT_THRESH 5e-4f   // f32 screen gap threshold, recurrent layer (err bound ~2e-5)

// ---------------------------------------------------------------------------
// Detect whether edge_index buffer is int64 (odd int32 words all zero) or int32
// ---------------------------------------------------------------------------
__global__ void detect_i64_kernel(const unsigned int* __restrict__ ei32, int* __restrict__ flag) {
    if (blockIdx.x == 0 && threadIdx.x == 0) {
        int allz = 1;
        for (int i = 1; i < 64; i += 2) allz &= (ei32[i] == 0u);
        *flag = allz;  // 1 -> int64, 0 -> int32
    }
}

__device__ __forceinline__ int rg_src(const void* ei, int is64, int E, int i) {
    return is64 ? (int)((const long long*)ei)[i] : ((const int*)ei)[i];
}
__device__ __forceinline__ int rg_dst(const void* ei, int is64, int E, int i) {
    return is64 ? (int)((const long long*)ei)[(long long)E + i] : ((const int*)ei)[(long long)E + i];
}

// ---------------------------------------------------------------------------
// Radix-partition CSR build. Bucket = dst>>9 (512 nodes/bucket, NB<=256).
// ---------------------------------------------------------------------------
__global__ __launch_bounds__(256) void bcount_kernel(const void* __restrict__ ei,
                                                     const int* __restrict__ flag,
                                                     int* __restrict__ bcnt, int E) {
    __shared__ int l[256];
    l[threadIdx.x] = 0;
    __syncthreads();
    int is64 = *flag;
    int stride = gridDim.x * 256;
    for (int i = blockIdx.x * 256 + threadIdx.x; i < E; i += stride) {
        int d = rg_dst(ei, is64, E, i);
        atomicAdd(&l[d >> 9], 1);
    }
    __syncthreads();
    if (l[threadIdx.x]) atomicAdd(&bcnt[threadIdx.x], l[threadIdx.x]);
}

__global__ __launch_bounds__(256) void bscan_kernel(const int* __restrict__ bcnt,
                                                    int* __restrict__ boff,
                                                    int* __restrict__ bcur,
                                                    int* __restrict__ row_off, int N) {
    __shared__ int buf[256];
    int t = threadIdx.x;
    int v = bcnt[t];
    buf[t] = v;
    __syncthreads();
    for (int off = 1; off < 256; off <<= 1) {
        int u = (t >= off) ? buf[t - off] : 0;
        __syncthreads();
        buf[t] += u;
        __syncthreads();
    }
    int excl = buf[t] - v;
    boff[t] = excl;
    bcur[t] = excl;
    if (t == 255) {
        boff[256] = buf[t];
        row_off[N] = buf[t];  // total edges
    }
}

__global__ __launch_bounds__(256) void part_kernel(const void* __restrict__ ei,
                                                   const int* __restrict__ flag,
                                                   int2* __restrict__ edge2,
                                                   int* __restrict__ bcur, int E) {
    __shared__ int lcnt[256];
    __shared__ int lbase[256];
    int is64 = *flag;
    int t = threadIdx.x;
    int nchunks = (E + 2047) / 2048;
    for (int c = blockIdx.x; c < nchunks; c += gridDim.x) {
        int base = c * 2048;
        lcnt[t] = 0;
        __syncthreads();
        int s[8], d[8], b[8];
#pragma unroll
        for (int j = 0; j < 8; ++j) {
            int i = base + j * 256 + t;
            if (i < E) {
                s[j] = rg_src(ei, is64, E, i);
                d[j] = rg_dst(ei, is64, E, i);
                b[j] = d[j] >> 9;
                atomicAdd(&lcnt[b[j]], 1);
            } else {
                b[j] = -1;
            }
        }
        __syncthreads();
        int lc = lcnt[t];
        if (lc) lbase[t] = atomicAdd(&bcur[t], lc);
        lcnt[t] = 0;
        __syncthreads();
#pragma unroll
        for (int j = 0; j < 8; ++j) {
            if (b[j] >= 0) {
                int r = atomicAdd(&lcnt[b[j]], 1);
                edge2[lbase[b[j]] + r] = make_int2(s[j], d[j]);
            }
        }
        __syncthreads();  // protect lcnt/lbase before next chunk reuses them
    }
}

__global__ __launch_bounds__(256) void csr_kernel(const int2* __restrict__ edge2,
                                                  const int* __restrict__ boff,
                                                  int* __restrict__ row_off,
                                                  int* __restrict__ adj, int N) {
    __shared__ int cnt[512];
    __shared__ int ps[256];
    int b = blockIdx.x;
    int t = threadIdx.x;
    int lo = b << 9;
    int ebase = boff[b], eend = boff[b + 1];
    cnt[t] = 0;
    cnt[t + 256] = 0;
    __syncthreads();
    for (int i = ebase + t; i < eend; i += 256) {
        int d = edge2[i].y;
        atomicAdd(&cnt[d - lo], 1);
    }
    __syncthreads();
    int c0 = cnt[2 * t], c1 = cnt[2 * t + 1];
    ps[t] = c0 + c1;
    __syncthreads();
    for (int off = 1; off < 256; off <<= 1) {
        int u = (t >= off) ? ps[t - off] : 0;
        __syncthreads();
        ps[t] += u;
        __syncthreads();
    }
    int excl = ps[t] - (c0 + c1);
    cnt[2 * t] = excl;          // becomes cursor
    cnt[2 * t + 1] = excl + c0;
    if (lo + 2 * t < N) row_off[lo + 2 * t] = ebase + excl;
    if (lo + 2 * t + 1 < N) row_off[lo + 2 * t + 1] = ebase + excl + c0;
    __syncthreads();
    for (int i = ebase + t; i < eend; i += 256) {
        int2 e = edge2[i];
        int p = atomicAdd(&cnt[e.y - lo], 1);
        adj[ebase + p] = e.x;  // row order nondeterministic; counting is order-invariant
    }
}

// ---------------------------------------------------------------------------
// Wave top-2 merge butterfly; tie-break smaller index (matches jnp.argmax).
// ---------------------------------------------------------------------------
__device__ __forceinline__ void top2_f32(float y, int lane, float& v1, int& i1, float& v2) {
    v1 = y; i1 = lane; v2 = -3.4e38f;
#pragma unroll
    for (int off = 32; off; off >>= 1) {
        float ov1 = __shfl_xor(v1, off);
        int oi1 = __shfl_xor(i1, off);
        float ov2 = __shfl_xor(v2, off);
        bool take = (ov1 > v1) || (ov1 == v1 && oi1 < i1);
        float nv2 = take ? fmaxf(v1, ov2) : fmaxf(v2, ov1);
        v1 = take ? ov1 : v1;
        i1 = take ? oi1 : i1;
        v2 = nv2;
    }
}

__device__ __forceinline__ int argmax_f64(double y, int lane) {
    double best = y;
    int bi = lane;
#pragma unroll
    for (int off = 32; off; off >>= 1) {
        double ov = __shfl_xor(best, off);
        int oi = __shfl_xor(bi, off);
        if (ov > best || (ov == best && oi < bi)) { best = ov; bi = oi; }
    }
    return bi;
}

// ---------------------------------------------------------------------------
// Full-wave ballot histogram (cold path): cnt = #in-neighbors state==lane, <=10
// ---------------------------------------------------------------------------
__device__ __forceinline__ int hist_count(const int* __restrict__ adj,
                                          const unsigned char* __restrict__ st_in,
                                          int beg, int end, int lane) {
    int cnt = 0;
    for (int base = beg; base < end; base += 64) {
        int idx = base + lane;
        unsigned long long valid = __ballot(idx < end);
        int sv = (idx < end) ? (int)st_in[adj[idx]] : 0;
        unsigned long long mm = valid;
#pragma unroll
        for (int b = 0; b < 6; ++b) {
            unsigned long long bl = __ballot(((sv >> b) & 1) != 0);
            mm &= ((lane >> b) & 1) ? bl : ~bl;
        }
        cnt += (int)__popcll(mm);
    }
    return cnt > 10 ? 10 : cnt;
}

// Byte butterfly pack (cold path only): count -> pk[16] bytes
__device__ __forceinline__ void pack_bytes(unsigned cmin, int lane, unsigned pk[16]) {
    unsigned v = cmin, p;
    p = __shfl_xor(v, 1); v = (lane & 1) ? (p | (v << 8)) : (v | (p << 8));
    p = __shfl_xor(v, 2); v = (lane & 2) ? (p | (v << 16)) : (v | (p << 16));
    unsigned q0, q1;
    p = __shfl_xor(v, 4); q0 = (lane & 4) ? p : v; q1 = (lane & 4) ? v : p;
    unsigned r0 = __shfl_xor(q0, 8), r1 = __shfl_xor(q1, 8);
    unsigned u0, u1, u2, u3;
    if (lane & 8) { u0 = r0; u1 = r1; u2 = q0; u3 = q1; }
    else          { u0 = q0; u1 = q1; u2 = r0; u3 = r1; }
    unsigned w0 = __shfl_xor(u0, 16), w1 = __shfl_xor(u1, 16),
             w2 = __shfl_xor(u2, 16), w3 = __shfl_xor(u3, 16);
    unsigned a0, a1, a2, a3, a4, a5, a6, a7;
    if (lane & 16) { a0 = w0; a1 = w1; a2 = w2; a3 = w3; a4 = u0; a5 = u1; a6 = u2; a7 = u3; }
    else           { a0 = u0; a1 = u1; a2 = u2; a3 = u3; a4 = w0; a5 = w1; a6 = w2; a7 = w3; }
    unsigned b0 = __shfl_xor(a0, 32), b1 = __shfl_xor(a1, 32), b2 = __shfl_xor(a2, 32),
             b3 = __shfl_xor(a3, 32), b4 = __shfl_xor(a4, 32), b5 = __shfl_xor(a5, 32),
             b6 = __shfl_xor(a6, 32), b7 = __shfl_xor(a7, 32);
    if (lane & 32) {
        pk[0] = b0; pk[1] = b1; pk[2] = b2; pk[3] = b3;
        pk[4] = b4; pk[5] = b5; pk[6] = b6; pk[7] = b7;
        pk[8] = a0; pk[9] = a1; pk[10] = a2; pk[11] = a3;
        pk[12] = a4; pk[13] = a5; pk[14] = a6; pk[15] = a7;
    } else {
        pk[0] = a0; pk[1] = a1; pk[2] = a2; pk[3] = a3;
        pk[4] = a4; pk[5] = a5; pk[6] = a6; pk[7] = a7;
        pk[8] = b0; pk[9] = b1; pk[10] = b2; pk[11] = b3;
        pk[12] = b4; pk[13] = b5; pk[14] = b6; pk[15] = b7;
    }
}

// ---------------------------------------------------------------------------
// Input layer: LDS-staged, software-pipelined (round-10 version).
// ---------------------------------------------------------------------------
__device__ __forceinline__ int input_f64_node(const float4* __restrict__ xr,
                                              const float* __restrict__ wsh,
                                              double bind, int lane) {
    double a0 = 0.0, a1 = 0.0, a2 = 0.0, a3 = 0.0;
#pragma unroll 8
    for (int k4 = 0; k4 < RG_IN / 4; ++k4) {
        float4 xv = xr[k4];
        int k = k4 * 4;
        a0 += (double)xv.x * (double)wsh[(k + 0) * RG_S + lane];
        a1 += (double)xv.y * (double)wsh[(k + 1) * RG_S + lane];
        a2 += (double)xv.z * (double)wsh[(k + 2) * RG_S + lane];
        a3 += (double)xv.w * (double)wsh[(k + 3) * RG_S + lane];
    }
    double acc = bind + ((a0 + a2) + (a1 + a3));
    return argmax_f64(acc, lane);
}

__global__ __launch_bounds__(256) void input_kernel(const float* __restrict__ x,
                                                    const float* __restrict__ W_in,
                                                    const float* __restrict__ b_in,
                                                    unsigned char* __restrict__ st, int n) {
    __shared__ float wsh[RG_IN * RG_S];   // 32 KB
    __shared__ float xs[4][8 * RG_IN];    // 16 KB: per-wave 8-row x buffer
    for (int i = threadIdx.x; i < RG_IN * RG_S; i += 256) wsh[i] = W_in[i];
    __syncthreads();
    int lane = threadIdx.x & 63;
    int wid = threadIdx.x >> 6;
    float binf = b_in[lane];
    double bind = (double)binf;
    float* myxs = xs[wid];
    int wave = blockIdx.x * 4 + wid;
    int nwaves = gridDim.x * 4;
    int nfull = n >> 3;

    if (wave < nfull) {
        int g = wave;
        float4 xr[4];
        {
            const float4* gp = (const float4*)(x + (size_t)g * 8 * RG_IN);
#pragma unroll
            for (int j = 0; j < 4; ++j) xr[j] = gp[lane + 64 * j];
        }
        while (true) {
#pragma unroll
            for (int j = 0; j < 4; ++j) ((float4*)myxs)[lane + 64 * j] = xr[j];
            int base = g * 8;
            int gn = g + nwaves;
            bool hasNext = gn < nfull;
            if (hasNext) {
                const float4* gp = (const float4*)(x + (size_t)gn * 8 * RG_IN);
#pragma unroll
                for (int j = 0; j < 4; ++j) xr[j] = gp[lane + 64 * j];
            }
            float acc[8][4];
#pragma unroll
            for (int j = 0; j < 8; ++j)
#pragma unroll
                for (int c = 0; c < 4; ++c) acc[j][c] = 0.f;
#pragma unroll 2
            for (int k4 = 0; k4 < RG_IN / 4; ++k4) {
                int k = k4 * 4;
                float w0 = wsh[(k + 0) * RG_S + lane];
                float w1 = wsh[(k + 1) * RG_S + lane];
                float w2 = wsh[(k + 2) * RG_S + lane];
                float w3 = wsh[(k + 3) * RG_S + lane];
#pragma unroll
                for (int j = 0; j < 8; ++j) {
                    float4 v = *(const float4*)&myxs[j * RG_IN + k4 * 4];
                    acc[j][0] += v.x * w0;
                    acc[j][1] += v.y * w1;
                    acc[j][2] += v.z * w2;
                    acc[j][3] += v.w * w3;
                }
            }
            int sres[8];
#pragma unroll
            for (int j = 0; j < 8; ++j) {
                float y = ((acc[j][0] + acc[j][2]) + (acc[j][1] + acc[j][3])) + binf;
                float v1f, v2f;
                int i1;
                top2_f32(y, lane, v1f, i1, v2f);
                sres[j] = (v1f - v2f < RG_IN_THRESH)
                              ? input_f64_node((const float4*)(x + (size_t)(base + j) * RG_IN),
                                               wsh, bind, lane)
                              : i1;
            }
            if (lane == 0) {
#pragma unroll
                for (int j = 0; j < 8; ++j) st[base + j] = (unsigned char)sres[j];
            }
            if (!hasNext) break;
            g = gn;
        }
    }
    for (int node = nfull * 8 + wave; node < n; node += nwaves) {
        const float4* xr4 = (const float4*)(x + (size_t)node * RG_IN);
        float f0 = 0.f, f1 = 0.f, f2 = 0.f, f3 = 0.f;
#pragma unroll 4
        for (int k4 = 0; k4 < RG_IN / 4; ++k4) {
            float4 xv = xr4[k4];
            int k = k4 * 4;
            f0 += xv.x * wsh[(k + 0) * RG_S + lane];
            f1 += xv.y * wsh[(k + 1) * RG_S + lane];
            f2 += xv.z * wsh[(k + 2) * RG_S + lane];
            f3 += xv.w * wsh[(k + 3) * RG_S + lane];
        }
        float y = ((f0 + f2) + (f1 + f3)) + binf;
        float v1f, v2f;
        int i1;
        top2_f32(y, lane, v1f, i1, v2f);
        int sres = (v1f - v2f < RG_IN_THRESH) ? input_f64_node(xr4, wsh, bind, lane) : i1;
        if (lane == 0) st[node] = (unsigned char)sres;
    }
}

// ---------------------------------------------------------------------------
// Recurrent iteration, phase 1 (hot): round-8/10 proven version, UNCHANGED.
// Only the launch grid changes: 1024 -> 1280 blocks fills the 5th wave slot
// per SIMD that VGPR=92 permits (512/92 = 5 waves/SIMD; 1024 blocks gave 4).
// ---------------------------------------------------------------------------
__global__ __launch_bounds__(256) void iter_screen_kernel(
    const int* __restrict__ row_off, const int* __restrict__ adj,
    const unsigned char* __restrict__ st_in, unsigned char* __restrict__ st_out,
    const float* __restrict__ W_rec, const float* __restrict__ b_rec,
    const float* __restrict__ bn_g, const float* __restrict__ bn_b,
    const float* __restrict__ bn_m, const float* __restrict__ bn_v,
    int* __restrict__ amb_cnt, int* __restrict__ amb_list, int n) {
    __shared__ unsigned int cslot[4][2][16];  // [wave][node A/B][64 byte counts]
    int lane = threadIdx.x & 63;
    int wid = threadIdx.x >> 6;
    int sub = lane & 31;
    bool hiHalf = lane >= 32;

    float s = bn_g[lane] * rsqrtf(bn_v[lane] + 1e-5f);
    float biasp = b_rec[lane] * s + (bn_b[lane] - bn_m[lane] * s);
    float wcol[RG_S];
#pragma unroll
    for (int k = 0; k < RG_S; ++k) wcol[k] = W_rec[k * RG_S + lane] * s;

    unsigned char* slotA = (unsigned char*)&cslot[wid][0][0];
    unsigned char* slotB = (unsigned char*)&cslot[wid][1][0];

    int wave = blockIdx.x * 4 + wid;
    int nwaves = gridDim.x * 4;
    for (int nA = wave; nA < n; nA += 2 * nwaves) {
        int nB = nA + nwaves;
        bool hasB = nB < n;
        int nBc = hasB ? nB : nA;
        int begA = row_off[nA], endA = row_off[nA + 1];
        int begB = row_off[nBc], endB = row_off[nBc + 1];
        int stoA = (int)st_in[nA];
        int stoB = (int)st_in[nBc];
        float wselfA = W_rec[(RG_S + stoA) * RG_S + lane] * s;
        float wselfB = W_rec[(RG_S + stoB) * RG_S + lane] * s;

        int myBeg = hiHalf ? begB : begA;
        int myDeg = hiHalf ? (endB - begB) : (endA - begA);
        int dA = endA - begA, dB = endB - begB;
        int dmax = dA > dB ? dA : dB;
        int cntA = 0, cntB = 0;
        for (int base = 0; base < dmax; base += 32) {
            int off = base + sub;
            bool v = off < myDeg;
            unsigned long long valid = __ballot(v);
            int sv = v ? (int)st_in[adj[myBeg + off]] : 0;
            unsigned long long mm = valid;
#pragma unroll
            for (int b = 0; b < 6; ++b) {
                unsigned long long bl = __ballot(((sv >> b) & 1) != 0);
                mm &= ((lane >> b) & 1) ? bl : ~bl;
            }
            cntA += (int)__popcll(mm & 0xFFFFFFFFull);
            cntB += (int)__popcll(mm >> 32);
        }
        slotA[lane] = (unsigned char)(cntA > 10 ? 10 : cntA);
        slotB[lane] = (unsigned char)(cntB > 10 ? 10 : cntB);

        // same-wave DS ordering: all lanes' byte writes precede these reads
        float yA0 = 0.f, yA1 = 0.f, yA2 = 0.f, yA3 = 0.f;
        float yB0 = 0.f, yB1 = 0.f, yB2 = 0.f, yB3 = 0.f;
#pragma unroll
        for (int g = 0; g < 16; ++g) {
            unsigned pA = cslot[wid][0][g];
            unsigned pB = cslot[wid][1][g];
            yA0 += (float)(pA & 0xFFu)         * wcol[4 * g + 0];
            yA1 += (float)((pA >> 8) & 0xFFu)  * wcol[4 * g + 1];
            yA2 += (float)((pA >> 16) & 0xFFu) * wcol[4 * g + 2];
            yA3 += (float)(pA >> 24)           * wcol[4 * g + 3];
            yB0 += (float)(pB & 0xFFu)         * wcol[4 * g + 0];
            yB1 += (float)((pB >> 8) & 0xFFu)  * wcol[4 * g + 1];
            yB2 += (float)((pB >> 16) & 0xFFu) * wcol[4 * g + 2];
            yB3 += (float)(pB >> 24)           * wcol[4 * g + 3];
        }
        float yA = ((yA0 + yA2) + (yA1 + yA3)) + biasp + wselfA;
        float v1, v2;
        int i1;
        top2_f32(yA, lane, v1, i1, v2);
        if (lane == 0) {
            st_out[nA] = (unsigned char)i1;
            if (v1 - v2 < RG_IT_THRESH) {
                int pidx = atomicAdd(amb_cnt, 1);
                amb_list[pidx] = nA;
            }
        }
        if (hasB) {
            float yB = ((yB0 + yB2) + (yB1 + yB3)) + biasp + wselfB;
            top2_f32(yB, lane, v1, i1, v2);
            if (lane == 0) {
                st_out[nB] = (unsigned char)i1;
                if (v1 - v2 < RG_IT_THRESH) {
                    int pidx = atomicAdd(amb_cnt, 1);
                    amb_list[pidx] = nB;
                }
            }
        }
    }
}

// ---------------------------------------------------------------------------
// Recurrent iteration, phase 2 (rare): exact f64 recompute for listed nodes.
// ---------------------------------------------------------------------------
__global__ __launch_bounds__(256) void iter_fix_kernel(
    const int* __restrict__ amb_cnt, const int* __restrict__ amb_list,
    const int* __restrict__ row_off, const int* __restrict__ adj,
    const unsigned char* __restrict__ st_in, unsigned char* __restrict__ st_out,
    const float* __restrict__ W_rec, const float* __restrict__ b_rec,
    const float* __restrict__ bn_g, const float* __restrict__ bn_b,
    const float* __restrict__ bn_m, const float* __restrict__ bn_v) {
    int tot = *amb_cnt;
    if (tot <= 0) return;
    int lane = threadIdx.x & 63;
    int wid = threadIdx.x >> 6;
    double brec = (double)b_rec[lane];
    double bnm = (double)bn_m[lane];
    double bns = (double)bn_g[lane] / sqrt((double)bn_v[lane] + RG_BN_EPS);
    double bnb = (double)bn_b[lane];
    int nw = gridDim.x * 4;
    for (int li = blockIdx.x * 4 + wid; li < tot; li += nw) {
        int node = amb_list[li];
        int beg = row_off[node], end = row_off[node + 1];
        int st_old = (int)st_in[node];
        float wself = W_rec[(RG_S + st_old) * RG_S + lane];
        int cmin = hist_count(adj, st_in, beg, end, lane);
        unsigned pk[16];
        pack_bytes((unsigned)cmin, lane, pk);
        double z0 = 0.0, z1 = 0.0, z2 = 0.0, z3 = 0.0;
#pragma unroll
        for (int g = 0; g < 16; ++g) {
            unsigned pg = pk[g];
            z0 += (double)(pg & 0xFFu)         * (double)W_rec[(4 * g + 0) * RG_S + lane];
            z1 += (double)((pg >> 8) & 0xFFu)  * (double)W_rec[(4 * g + 1) * RG_S + lane];
            z2 += (double)((pg >> 16) & 0xFFu) * (double)W_rec[(4 * g + 2) * RG_S + lane];
            z3 += (double)(pg >> 24)           * (double)W_rec[(4 * g + 3) * RG_S + lane];
        }
        double z = ((z0 + z2) + (z1 + z3)) + brec + (double)wself;
        double y = (z - bnm) * bns + bnb;
        int st_res = argmax_f64(y, lane);
        if (lane == 0) st_out[node] = (unsigned char)st_res;
    }
}

// ---------------------------------------------------------------------------
// Output MLP collapses to a 64x8 lookup table over the final state
// ---------------------------------------------------------------------------
__global__ void table_kernel(const float* __restrict__ Wo1, const float* __restrict__ bo1,
                             const float* __restrict__ g, const float* __restrict__ b,
                             const float* __restrict__ m, const float* __restrict__ v,
                             const float* __restrict__ Wo2, const float* __restrict__ bo2,
                             float* __restrict__ table) {
    int k = threadIdx.x;
    if (k >= RG_S) return;
    double h[RG_H];
#pragma unroll
    for (int j = 0; j < RG_H; ++j) {
        double z = (double)Wo1[k * RG_H + j] + (double)bo1[j];
        double y = (z - (double)m[j]) * ((double)g[j] / sqrt((double)v[j] + RG_BN_EPS)) +
                   (double)b[j];
        h[j] = y > 0.0 ? y : 0.0;
    }
#pragma unroll
    for (int o = 0; o < RG_OUT; ++o) {
        double acc = (double)bo2[o];
#pragma unroll
        for (int j = 0; j < RG_H; ++j) acc += h[j] * (double)Wo2[j * RG_OUT + o];
        table[k * RG_OUT + o] = (float)acc;
    }
}

__global__ void out_kernel(const unsigned char* __restrict__ st, const float* __restrict__ table,
                           float* __restrict__ out, int n) {
    int i = blockIdx.x * blockDim.x + threadIdx.x;
    if (i >= n) return;
    int s = (int)st[i];
    float4 a = ((const float4*)table)[s * 2];
    float4 b = ((const float4*)table)[s * 2 + 1];
    ((float4*)out)[(size_t)i * 2] = a;
    ((float4*)out)[(size_t)i * 2 + 1] = b;
}

// ---------------------------------------------------------------------------
extern "C" void kernel_launch(void* const* d_in, const int* in_sizes, int n_in,
                              void* d_out, int out_size, void* d_ws, size_t ws_size,
                              hipStream_t stream) {
    const float* x     = (const float*)d_in[0];
    const void*  ei    = d_in[1];
    const float* W_in  = (const float*)d_in[2];
    const float* b_in  = (const float*)d_in[3];
    const float* W_rec = (const float*)d_in[4];
    const float* b_rec = (const float*)d_in[5];
    const float* bn_g  = (const float*)d_in[6];
    const float* bn_b  = (const float*)d_in[7];
    const float* bn_m  = (const float*)d_in[8];
    const float* bn_v  = (const float*)d_in[9];
    const float* Wo1   = (const float*)d_in[10];
    const float* bo1   = (const float*)d_in[11];
    const float* bno_g = (const float*)d_in[12];
    const float* bno_b = (const float*)d_in[13];
    const float* bno_m = (const float*)d_in[14];
    const float* bno_v = (const float*)d_in[15];
    const float* Wo2   = (const float*)d_in[16];
    const float* bo2   = (const float*)d_in[17];

    int N = in_sizes[0] / RG_IN;
    int E = in_sizes[1] / 2;
    int NB = (N + 511) >> 9;  // buckets of 512 nodes; <=256 for N<=131072

    char* ws = (char*)d_ws;
    size_t off = 0;
    auto alloc = [&](size_t bytes) -> void* {
        void* p = ws + off;
        off = (off + bytes + 255) & ~(size_t)255;
        return p;
    };
    int*           flag    = (int*)alloc(sizeof(int));
    int*           bcnt    = (int*)alloc(256 * sizeof(int));
    int*           boff    = (int*)alloc(257 * sizeof(int));
    int*           bcur    = (int*)alloc(256 * sizeof(int));
    int*           row_off = (int*)alloc((size_t)(N + 1) * sizeof(int));
    int*           adj     = (int*)alloc((size_t)E * sizeof(int));
    int2*          edge2   = (int2*)alloc((size_t)E * sizeof(int2));
    unsigned char* stA     = (unsigned char*)alloc((size_t)N);
    unsigned char* stB     = (unsigned char*)alloc((size_t)N);
    int*           ambc    = (int*)alloc(RG_ITERS * sizeof(int));
    int*           ambl    = (int*)alloc((size_t)N * sizeof(int));
    float*         table   = (float*)alloc(RG_S * RG_OUT * sizeof(float));

    hipMemsetAsync(bcnt, 0, 256 * sizeof(int), stream);
    hipMemsetAsync(ambc, 0, RG_ITERS * sizeof(int), stream);
    detect_i64_kernel<<<1, 64, 0, stream>>>((const unsigned int*)ei, flag);

    bcount_kernel<<<512, 256, 0, stream>>>(ei, flag, bcnt, E);
    bscan_kernel<<<1, 256, 0, stream>>>(bcnt, boff, bcur, row_off, N);
    part_kernel<<<1024, 256, 0, stream>>>(ei, flag, edge2, bcur, E);
    csr_kernel<<<NB, 256, 0, stream>>>(edge2, boff, row_off, adj, N);

    input_kernel<<<768, 256, 0, stream>>>(x, W_in, b_in, stA, N);

    unsigned char* sin = stA;
    unsigned char* sout = stB;
    for (int it = 0; it < RG_ITERS; ++it) {
        iter_screen_kernel<<<1280, 256, 0, stream>>>(row_off, adj, sin, sout, W_rec, b_rec,
                                                     bn_g, bn_b, bn_m, bn_v,
                                                     ambc + it, ambl, N);
        iter_fix_kernel<<<128, 256, 0, stream>>>(ambc + it, ambl, row_off, adj, sin, sout,
                                                 W_rec, b_rec, bn_g, bn_b, bn_m, bn_v);
        unsigned char* t = sin; sin = sout; sout = t;
    }

    table_kernel<<<1, 64, 0, stream>>>(Wo1, bo1, bno_g, bno_b, bno_m, bno_v, Wo2, bo2, table);
    out_kernel<<<(N + 255) / 256, 256, 0, stream>>>(sin, table, (float*)d_out, N);
}

// Round 16
// 877.720 us; speedup vs baseline: 1.0499x; 1.0499x over previous
//
#include <hip/hip_runtime.h>

#define RG_ITERS 12
#define RG_S 64
#define RG_IN 128
#define RG_H 16
#define RG_OUT 8
#define RG_BN_EPS 1e-5
#define RG_IN_THRESH 2e-3f   // f32 screen gap threshold, input layer (err bound ~1e-5)
#define RG_IT_THRESH 5e-4f   // f32 screen gap threshold, recurrent layer (err bound ~2e-5)

// ---------------------------------------------------------------------------
// Detect whether edge_index buffer is int64 (odd int32 words all zero) or int32
// ---------------------------------------------------------------------------
__global__ void detect_i64_kernel(const unsigned int* __restrict__ ei32, int* __restrict__ flag) {
    if (blockIdx.x == 0 && threadIdx.x == 0) {
        int allz = 1;
        for (int i = 1; i < 64; i += 2) allz &= (ei32[i] == 0u);
        *flag = allz;  // 1 -> int64, 0 -> int32
    }
}

__device__ __forceinline__ int rg_src(const void* ei, int is64, int E, int i) {
    return is64 ? (int)((const long long*)ei)[i] : ((const int*)ei)[i];
}
__device__ __forceinline__ int rg_dst(const void* ei, int is64, int E, int i) {
    return is64 ? (int)((const long long*)ei)[(long long)E + i] : ((const int*)ei)[(long long)E + i];
}

// ---------------------------------------------------------------------------
// Radix-partition CSR build. Bucket = dst>>9 (512 nodes/bucket, NB<=256).
// ---------------------------------------------------------------------------
__global__ __launch_bounds__(256) void bcount_kernel(const void* __restrict__ ei,
                                                     const int* __restrict__ flag,
                                                     int* __restrict__ bcnt, int E) {
    __shared__ int l[256];
    l[threadIdx.x] = 0;
    __syncthreads();
    int is64 = *flag;
    int stride = gridDim.x * 256;
    for (int i = blockIdx.x * 256 + threadIdx.x; i < E; i += stride) {
        int d = rg_dst(ei, is64, E, i);
        atomicAdd(&l[d >> 9], 1);
    }
    __syncthreads();
    if (l[threadIdx.x]) atomicAdd(&bcnt[threadIdx.x], l[threadIdx.x]);
}

__global__ __launch_bounds__(256) void bscan_kernel(const int* __restrict__ bcnt,
                                                    int* __restrict__ boff,
                                                    int* __restrict__ bcur,
                                                    int* __restrict__ row_off, int N) {
    __shared__ int buf[256];
    int t = threadIdx.x;
    int v = bcnt[t];
    buf[t] = v;
    __syncthreads();
    for (int off = 1; off < 256; off <<= 1) {
        int u = (t >= off) ? buf[t - off] : 0;
        __syncthreads();
        buf[t] += u;
        __syncthreads();
    }
    int excl = buf[t] - v;
    boff[t] = excl;
    bcur[t] = excl;
    if (t == 255) {
        boff[256] = buf[t];
        row_off[N] = buf[t];  // total edges
    }
}

__global__ __launch_bounds__(256) void part_kernel(const void* __restrict__ ei,
                                                   const int* __restrict__ flag,
                                                   int2* __restrict__ edge2,
                                                   int* __restrict__ bcur, int E) {
    __shared__ int lcnt[256];
    __shared__ int lbase[256];
    int is64 = *flag;
    int t = threadIdx.x;
    int nchunks = (E + 2047) / 2048;
    for (int c = blockIdx.x; c < nchunks; c += gridDim.x) {
        int base = c * 2048;
        lcnt[t] = 0;
        __syncthreads();
        int s[8], d[8], b[8];
#pragma unroll
        for (int j = 0; j < 8; ++j) {
            int i = base + j * 256 + t;
            if (i < E) {
                s[j] = rg_src(ei, is64, E, i);
                d[j] = rg_dst(ei, is64, E, i);
                b[j] = d[j] >> 9;
                atomicAdd(&lcnt[b[j]], 1);
            } else {
                b[j] = -1;
            }
        }
        __syncthreads();
        int lc = lcnt[t];
        if (lc) lbase[t] = atomicAdd(&bcur[t], lc);
        lcnt[t] = 0;
        __syncthreads();
#pragma unroll
        for (int j = 0; j < 8; ++j) {
            if (b[j] >= 0) {
                int r = atomicAdd(&lcnt[b[j]], 1);
                edge2[lbase[b[j]] + r] = make_int2(s[j], d[j]);
            }
        }
        __syncthreads();  // protect lcnt/lbase before next chunk reuses them
    }
}

__global__ __launch_bounds__(256) void csr_kernel(const int2* __restrict__ edge2,
                                                  const int* __restrict__ boff,
                                                  int* __restrict__ row_off,
                                                  int* __restrict__ adj, int N) {
    __shared__ int cnt[512];
    __shared__ int ps[256];
    int b = blockIdx.x;
    int t = threadIdx.x;
    int lo = b << 9;
    int ebase = boff[b], eend = boff[b + 1];
    cnt[t] = 0;
    cnt[t + 256] = 0;
    __syncthreads();
    for (int i = ebase + t; i < eend; i += 256) {
        int d = edge2[i].y;
        atomicAdd(&cnt[d - lo], 1);
    }
    __syncthreads();
    int c0 = cnt[2 * t], c1 = cnt[2 * t + 1];
    ps[t] = c0 + c1;
    __syncthreads();
    for (int off = 1; off < 256; off <<= 1) {
        int u = (t >= off) ? ps[t - off] : 0;
        __syncthreads();
        ps[t] += u;
        __syncthreads();
    }
    int excl = ps[t] - (c0 + c1);
    cnt[2 * t] = excl;          // becomes cursor
    cnt[2 * t + 1] = excl + c0;
    if (lo + 2 * t < N) row_off[lo + 2 * t] = ebase + excl;
    if (lo + 2 * t + 1 < N) row_off[lo + 2 * t + 1] = ebase + excl + c0;
    __syncthreads();
    for (int i = ebase + t; i < eend; i += 256) {
        int2 e = edge2[i];
        int p = atomicAdd(&cnt[e.y - lo], 1);
        adj[ebase + p] = e.x;  // row order nondeterministic; counting is order-invariant
    }
}

// ---------------------------------------------------------------------------
// Wave top-2 merge butterfly; tie-break smaller index (matches jnp.argmax).
// ---------------------------------------------------------------------------
__device__ __forceinline__ void top2_f32(float y, int lane, float& v1, int& i1, float& v2) {
    v1 = y; i1 = lane; v2 = -3.4e38f;
#pragma unroll
    for (int off = 32; off; off >>= 1) {
        float ov1 = __shfl_xor(v1, off);
        int oi1 = __shfl_xor(i1, off);
        float ov2 = __shfl_xor(v2, off);
        bool take = (ov1 > v1) || (ov1 == v1 && oi1 < i1);
        float nv2 = take ? fmaxf(v1, ov2) : fmaxf(v2, ov1);
        v1 = take ? ov1 : v1;
        i1 = take ? oi1 : i1;
        v2 = nv2;
    }
}

__device__ __forceinline__ int argmax_f64(double y, int lane) {
    double best = y;
    int bi = lane;
#pragma unroll
    for (int off = 32; off; off >>= 1) {
        double ov = __shfl_xor(best, off);
        int oi = __shfl_xor(bi, off);
        if (ov > best || (ov == best && oi < bi)) { best = ov; bi = oi; }
    }
    return bi;
}

// ---------------------------------------------------------------------------
// Full-wave ballot histogram (cold path): cnt = #in-neighbors state==lane, <=10
// ---------------------------------------------------------------------------
__device__ __forceinline__ int hist_count(const int* __restrict__ adj,
                                          const unsigned char* __restrict__ st_in,
                                          int beg, int end, int lane) {
    int cnt = 0;
    for (int base = beg; base < end; base += 64) {
        int idx = base + lane;
        unsigned long long valid = __ballot(idx < end);
        int sv = (idx < end) ? (int)st_in[adj[idx]] : 0;
        unsigned long long mm = valid;
#pragma unroll
        for (int b = 0; b < 6; ++b) {
            unsigned long long bl = __ballot(((sv >> b) & 1) != 0);
            mm &= ((lane >> b) & 1) ? bl : ~bl;
        }
        cnt += (int)__popcll(mm);
    }
    return cnt > 10 ? 10 : cnt;
}

// Byte butterfly pack (cold path only): count -> pk[16] bytes
__device__ __forceinline__ void pack_bytes(unsigned cmin, int lane, unsigned pk[16]) {
    unsigned v = cmin, p;
    p = __shfl_xor(v, 1); v = (lane & 1) ? (p | (v << 8)) : (v | (p << 8));
    p = __shfl_xor(v, 2); v = (lane & 2) ? (p | (v << 16)) : (v | (p << 16));
    unsigned q0, q1;
    p = __shfl_xor(v, 4); q0 = (lane & 4) ? p : v; q1 = (lane & 4) ? v : p;
    unsigned r0 = __shfl_xor(q0, 8), r1 = __shfl_xor(q1, 8);
    unsigned u0, u1, u2, u3;
    if (lane & 8) { u0 = r0; u1 = r1; u2 = q0; u3 = q1; }
    else          { u0 = q0; u1 = q1; u2 = r0; u3 = r1; }
    unsigned w0 = __shfl_xor(u0, 16), w1 = __shfl_xor(u1, 16),
             w2 = __shfl_xor(u2, 16), w3 = __shfl_xor(u3, 16);
    unsigned a0, a1, a2, a3, a4, a5, a6, a7;
    if (lane & 16) { a0 = w0; a1 = w1; a2 = w2; a3 = w3; a4 = u0; a5 = u1; a6 = u2; a7 = u3; }
    else           { a0 = u0; a1 = u1; a2 = u2; a3 = u3; a4 = w0; a5 = w1; a6 = w2; a7 = w3; }
    unsigned b0 = __shfl_xor(a0, 32), b1 = __shfl_xor(a1, 32), b2 = __shfl_xor(a2, 32),
             b3 = __shfl_xor(a3, 32), b4 = __shfl_xor(a4, 32), b5 = __shfl_xor(a5, 32),
             b6 = __shfl_xor(a6, 32), b7 = __shfl_xor(a7, 32);
    if (lane & 32) {
        pk[0] = b0; pk[1] = b1; pk[2] = b2; pk[3] = b3;
        pk[4] = b4; pk[5] = b5; pk[6] = b6; pk[7] = b7;
        pk[8] = a0; pk[9] = a1; pk[10] = a2; pk[11] = a3;
        pk[12] = a4; pk[13] = a5; pk[14] = a6; pk[15] = a7;
    } else {
        pk[0] = a0; pk[1] = a1; pk[2] = a2; pk[3] = a3;
        pk[4] = a4; pk[5] = a5; pk[6] = a6; pk[7] = a7;
        pk[8] = b0; pk[9] = b1; pk[10] = b2; pk[11] = b3;
        pk[12] = b4; pk[13] = b5; pk[14] = b6; pk[15] = b7;
    }
}

// ---------------------------------------------------------------------------
// Input layer: LDS-staged, software-pipelined (round-10 version).
// ---------------------------------------------------------------------------
__device__ __forceinline__ int input_f64_node(const float4* __restrict__ xr,
                                              const float* __restrict__ wsh,
                                              double bind, int lane) {
    double a0 = 0.0, a1 = 0.0, a2 = 0.0, a3 = 0.0;
#pragma unroll 8
    for (int k4 = 0; k4 < RG_IN / 4; ++k4) {
        float4 xv = xr[k4];
        int k = k4 * 4;
        a0 += (double)xv.x * (double)wsh[(k + 0) * RG_S + lane];
        a1 += (double)xv.y * (double)wsh[(k + 1) * RG_S + lane];
        a2 += (double)xv.z * (double)wsh[(k + 2) * RG_S + lane];
        a3 += (double)xv.w * (double)wsh[(k + 3) * RG_S + lane];
    }
    double acc = bind + ((a0 + a2) + (a1 + a3));
    return argmax_f64(acc, lane);
}

__global__ __launch_bounds__(256) void input_kernel(const float* __restrict__ x,
                                                    const float* __restrict__ W_in,
                                                    const float* __restrict__ b_in,
                                                    unsigned char* __restrict__ st, int n) {
    __shared__ float wsh[RG_IN * RG_S];   // 32 KB
    __shared__ float xs[4][8 * RG_IN];    // 16 KB: per-wave 8-row x buffer
    for (int i = threadIdx.x; i < RG_IN * RG_S; i += 256) wsh[i] = W_in[i];
    __syncthreads();
    int lane = threadIdx.x & 63;
    int wid = threadIdx.x >> 6;
    float binf = b_in[lane];
    double bind = (double)binf;
    float* myxs = xs[wid];
    int wave = blockIdx.x * 4 + wid;
    int nwaves = gridDim.x * 4;
    int nfull = n >> 3;

    if (wave < nfull) {
        int g = wave;
        float4 xr[4];
        {
            const float4* gp = (const float4*)(x + (size_t)g * 8 * RG_IN);
#pragma unroll
            for (int j = 0; j < 4; ++j) xr[j] = gp[lane + 64 * j];
        }
        while (true) {
#pragma unroll
            for (int j = 0; j < 4; ++j) ((float4*)myxs)[lane + 64 * j] = xr[j];
            int base = g * 8;
            int gn = g + nwaves;
            bool hasNext = gn < nfull;
            if (hasNext) {
                const float4* gp = (const float4*)(x + (size_t)gn * 8 * RG_IN);
#pragma unroll
                for (int j = 0; j < 4; ++j) xr[j] = gp[lane + 64 * j];
            }
            float acc[8][4];
#pragma unroll
            for (int j = 0; j < 8; ++j)
#pragma unroll
                for (int c = 0; c < 4; ++c) acc[j][c] = 0.f;
#pragma unroll 2
            for (int k4 = 0; k4 < RG_IN / 4; ++k4) {
                int k = k4 * 4;
                float w0 = wsh[(k + 0) * RG_S + lane];
                float w1 = wsh[(k + 1) * RG_S + lane];
                float w2 = wsh[(k + 2) * RG_S + lane];
                float w3 = wsh[(k + 3) * RG_S + lane];
#pragma unroll
                for (int j = 0; j < 8; ++j) {
                    float4 v = *(const float4*)&myxs[j * RG_IN + k4 * 4];
                    acc[j][0] += v.x * w0;
                    acc[j][1] += v.y * w1;
                    acc[j][2] += v.z * w2;
                    acc[j][3] += v.w * w3;
                }
            }
            int sres[8];
#pragma unroll
            for (int j = 0; j < 8; ++j) {
                float y = ((acc[j][0] + acc[j][2]) + (acc[j][1] + acc[j][3])) + binf;
                float v1f, v2f;
                int i1;
                top2_f32(y, lane, v1f, i1, v2f);
                sres[j] = (v1f - v2f < RG_IN_THRESH)
                              ? input_f64_node((const float4*)(x + (size_t)(base + j) * RG_IN),
                                               wsh, bind, lane)
                              : i1;
            }
            if (lane == 0) {
#pragma unroll
                for (int j = 0; j < 8; ++j) st[base + j] = (unsigned char)sres[j];
            }
            if (!hasNext) break;
            g = gn;
        }
    }
    for (int node = nfull * 8 + wave; node < n; node += nwaves) {
        const float4* xr4 = (const float4*)(x + (size_t)node * RG_IN);
        float f0 = 0.f, f1 = 0.f, f2 = 0.f, f3 = 0.f;
#pragma unroll 4
        for (int k4 = 0; k4 < RG_IN / 4; ++k4) {
            float4 xv = xr4[k4];
            int k = k4 * 4;
            f0 += xv.x * wsh[(k + 0) * RG_S + lane];
            f1 += xv.y * wsh[(k + 1) * RG_S + lane];
            f2 += xv.z * wsh[(k + 2) * RG_S + lane];
            f3 += xv.w * wsh[(k + 3) * RG_S + lane];
        }
        float y = ((f0 + f2) + (f1 + f3)) + binf;
        float v1f, v2f;
        int i1;
        top2_f32(y, lane, v1f, i1, v2f);
        int sres = (v1f - v2f < RG_IN_THRESH) ? input_f64_node(xr4, wsh, bind, lane) : i1;
        if (lane == 0) st[node] = (unsigned char)sres;
    }
}

// ---------------------------------------------------------------------------
// Recurrent iteration, phase 1 (hot): round-8/10 proven version, grid 1024.
// (r15 lesson: VGPR=92 hard-caps 4 waves/SIMD — occupancy steps at 64/128/256
// VGPR on gfx950 — so grid 1024 = 4 blocks/CU is exactly resident; 1280 adds
// a serialized tail pass and regressed. This config measured 876-877 us 2x.)
// ---------------------------------------------------------------------------
__global__ __launch_bounds__(256) void iter_screen_kernel(
    const int* __restrict__ row_off, const int* __restrict__ adj,
    const unsigned char* __restrict__ st_in, unsigned char* __restrict__ st_out,
    const float* __restrict__ W_rec, const float* __restrict__ b_rec,
    const float* __restrict__ bn_g, const float* __restrict__ bn_b,
    const float* __restrict__ bn_m, const float* __restrict__ bn_v,
    int* __restrict__ amb_cnt, int* __restrict__ amb_list, int n) {
    __shared__ unsigned int cslot[4][2][16];  // [wave][node A/B][64 byte counts]
    int lane = threadIdx.x & 63;
    int wid = threadIdx.x >> 6;
    int sub = lane & 31;
    bool hiHalf = lane >= 32;

    float s = bn_g[lane] * rsqrtf(bn_v[lane] + 1e-5f);
    float biasp = b_rec[lane] * s + (bn_b[lane] - bn_m[lane] * s);
    float wcol[RG_S];
#pragma unroll
    for (int k = 0; k < RG_S; ++k) wcol[k] = W_rec[k * RG_S + lane] * s;

    unsigned char* slotA = (unsigned char*)&cslot[wid][0][0];
    unsigned char* slotB = (unsigned char*)&cslot[wid][1][0];

    int wave = blockIdx.x * 4 + wid;
    int nwaves = gridDim.x * 4;
    for (int nA = wave; nA < n; nA += 2 * nwaves) {
        int nB = nA + nwaves;
        bool hasB = nB < n;
        int nBc = hasB ? nB : nA;
        int begA = row_off[nA], endA = row_off[nA + 1];
        int begB = row_off[nBc], endB = row_off[nBc + 1];
        int stoA = (int)st_in[nA];
        int stoB = (int)st_in[nBc];
        float wselfA = W_rec[(RG_S + stoA) * RG_S + lane] * s;
        float wselfB = W_rec[(RG_S + stoB) * RG_S + lane] * s;

        int myBeg = hiHalf ? begB : begA;
        int myDeg = hiHalf ? (endB - begB) : (endA - begA);
        int dA = endA - begA, dB = endB - begB;
        int dmax = dA > dB ? dA : dB;
        int cntA = 0, cntB = 0;
        for (int base = 0; base < dmax; base += 32) {
            int off = base + sub;
            bool v = off < myDeg;
            unsigned long long valid = __ballot(v);
            int sv = v ? (int)st_in[adj[myBeg + off]] : 0;
            unsigned long long mm = valid;
#pragma unroll
            for (int b = 0; b < 6; ++b) {
                unsigned long long bl = __ballot(((sv >> b) & 1) != 0);
                mm &= ((lane >> b) & 1) ? bl : ~bl;
            }
            cntA += (int)__popcll(mm & 0xFFFFFFFFull);
            cntB += (int)__popcll(mm >> 32);
        }
        slotA[lane] = (unsigned char)(cntA > 10 ? 10 : cntA);
        slotB[lane] = (unsigned char)(cntB > 10 ? 10 : cntB);

        // same-wave DS ordering: all lanes' byte writes precede these reads
        float yA0 = 0.f, yA1 = 0.f, yA2 = 0.f, yA3 = 0.f;
        float yB0 = 0.f, yB1 = 0.f, yB2 = 0.f, yB3 = 0.f;
#pragma unroll
        for (int g = 0; g < 16; ++g) {
            unsigned pA = cslot[wid][0][g];
            unsigned pB = cslot[wid][1][g];
            yA0 += (float)(pA & 0xFFu)         * wcol[4 * g + 0];
            yA1 += (float)((pA >> 8) & 0xFFu)  * wcol[4 * g + 1];
            yA2 += (float)((pA >> 16) & 0xFFu) * wcol[4 * g + 2];
            yA3 += (float)(pA >> 24)           * wcol[4 * g + 3];
            yB0 += (float)(pB & 0xFFu)         * wcol[4 * g + 0];
            yB1 += (float)((pB >> 8) & 0xFFu)  * wcol[4 * g + 1];
            yB2 += (float)((pB >> 16) & 0xFFu) * wcol[4 * g + 2];
            yB3 += (float)(pB >> 24)           * wcol[4 * g + 3];
        }
        float yA = ((yA0 + yA2) + (yA1 + yA3)) + biasp + wselfA;
        float v1, v2;
        int i1;
        top2_f32(yA, lane, v1, i1, v2);
        if (lane == 0) {
            st_out[nA] = (unsigned char)i1;
            if (v1 - v2 < RG_IT_THRESH) {
                int pidx = atomicAdd(amb_cnt, 1);
                amb_list[pidx] = nA;
            }
        }
        if (hasB) {
            float yB = ((yB0 + yB2) + (yB1 + yB3)) + biasp + wselfB;
            top2_f32(yB, lane, v1, i1, v2);
            if (lane == 0) {
                st_out[nB] = (unsigned char)i1;
                if (v1 - v2 < RG_IT_THRESH) {
                    int pidx = atomicAdd(amb_cnt, 1);
                    amb_list[pidx] = nB;
                }
            }
        }
    }
}

// ---------------------------------------------------------------------------
// Recurrent iteration, phase 2 (rare): exact f64 recompute for listed nodes.
// ---------------------------------------------------------------------------
__global__ __launch_bounds__(256) void iter_fix_kernel(
    const int* __restrict__ amb_cnt, const int* __restrict__ amb_list,
    const int* __restrict__ row_off, const int* __restrict__ adj,
    const unsigned char* __restrict__ st_in, unsigned char* __restrict__ st_out,
    const float* __restrict__ W_rec, const float* __restrict__ b_rec,
    const float* __restrict__ bn_g, const float* __restrict__ bn_b,
    const float* __restrict__ bn_m, const float* __restrict__ bn_v) {
    int tot = *amb_cnt;
    if (tot <= 0) return;
    int lane = threadIdx.x & 63;
    int wid = threadIdx.x >> 6;
    double brec = (double)b_rec[lane];
    double bnm = (double)bn_m[lane];
    double bns = (double)bn_g[lane] / sqrt((double)bn_v[lane] + RG_BN_EPS);
    double bnb = (double)bn_b[lane];
    int nw = gridDim.x * 4;
    for (int li = blockIdx.x * 4 + wid; li < tot; li += nw) {
        int node = amb_list[li];
        int beg = row_off[node], end = row_off[node + 1];
        int st_old = (int)st_in[node];
        float wself = W_rec[(RG_S + st_old) * RG_S + lane];
        int cmin = hist_count(adj, st_in, beg, end, lane);
        unsigned pk[16];
        pack_bytes((unsigned)cmin, lane, pk);
        double z0 = 0.0, z1 = 0.0, z2 = 0.0, z3 = 0.0;
#pragma unroll
        for (int g = 0; g < 16; ++g) {
            unsigned pg = pk[g];
            z0 += (double)(pg & 0xFFu)         * (double)W_rec[(4 * g + 0) * RG_S + lane];
            z1 += (double)((pg >> 8) & 0xFFu)  * (double)W_rec[(4 * g + 1) * RG_S + lane];
            z2 += (double)((pg >> 16) & 0xFFu) * (double)W_rec[(4 * g + 2) * RG_S + lane];
            z3 += (double)(pg >> 24)           * (double)W_rec[(4 * g + 3) * RG_S + lane];
        }
        double z = ((z0 + z2) + (z1 + z3)) + brec + (double)wself;
        double y = (z - bnm) * bns + bnb;
        int st_res = argmax_f64(y, lane);
        if (lane == 0) st_out[node] = (unsigned char)st_res;
    }
}

// ---------------------------------------------------------------------------
// Output MLP collapses to a 64x8 lookup table over the final state
// ---------------------------------------------------------------------------
__global__ void table_kernel(const float* __restrict__ Wo1, const float* __restrict__ bo1,
                             const float* __restrict__ g, const float* __restrict__ b,
                             const float* __restrict__ m, const float* __restrict__ v,
                             const float* __restrict__ Wo2, const float* __restrict__ bo2,
                             float* __restrict__ table) {
    int k = threadIdx.x;
    if (k >= RG_S) return;
    double h[RG_H];
#pragma unroll
    for (int j = 0; j < RG_H; ++j) {
        double z = (double)Wo1[k * RG_H + j] + (double)bo1[j];
        double y = (z - (double)m[j]) * ((double)g[j] / sqrt((double)v[j] + RG_BN_EPS)) +
                   (double)b[j];
        h[j] = y > 0.0 ? y : 0.0;
    }
#pragma unroll
    for (int o = 0; o < RG_OUT; ++o) {
        double acc = (double)bo2[o];
#pragma unroll
        for (int j = 0; j < RG_H; ++j) acc += h[j] * (double)Wo2[j * RG_OUT + o];
        table[k * RG_OUT + o] = (float)acc;
    }
}

__global__ void out_kernel(const unsigned char* __restrict__ st, const float* __restrict__ table,
                           float* __restrict__ out, int n) {
    int i = blockIdx.x * blockDim.x + threadIdx.x;
    if (i >= n) return;
    int s = (int)st[i];
    float4 a = ((const float4*)table)[s * 2];
    float4 b = ((const float4*)table)[s * 2 + 1];
    ((float4*)out)[(size_t)i * 2] = a;
    ((float4*)out)[(size_t)i * 2 + 1] = b;
}

// ---------------------------------------------------------------------------
extern "C" void kernel_launch(void* const* d_in, const int* in_sizes, int n_in,
                              void* d_out, int out_size, void* d_ws, size_t ws_size,
                              hipStream_t stream) {
    const float* x     = (const float*)d_in[0];
    const void*  ei    = d_in[1];
    const float* W_in  = (const float*)d_in[2];
    const float* b_in  = (const float*)d_in[3];
    const float* W_rec = (const float*)d_in[4];
    const float* b_rec = (const float*)d_in[5];
    const float* bn_g  = (const float*)d_in[6];
    const float* bn_b  = (const float*)d_in[7];
    const float* bn_m  = (const float*)d_in[8];
    const float* bn_v  = (const float*)d_in[9];
    const float* Wo1   = (const float*)d_in[10];
    const float* bo1   = (const float*)d_in[11];
    const float* bno_g = (const float*)d_in[12];
    const float* bno_b = (const float*)d_in[13];
    const float* bno_m = (const float*)d_in[14];
    const float* bno_v = (const float*)d_in[15];
    const float* Wo2   = (const float*)d_in[16];
    const float* bo2   = (const float*)d_in[17];

    int N = in_sizes[0] / RG_IN;
    int E = in_sizes[1] / 2;
    int NB = (N + 511) >> 9;  // buckets of 512 nodes; <=256 for N<=131072

    char* ws = (char*)d_ws;
    size_t off = 0;
    auto alloc = [&](size_t bytes) -> void* {
        void* p = ws + off;
        off = (off + bytes + 255) & ~(size_t)255;
        return p;
    };
    int*           flag    = (int*)alloc(sizeof(int));
    int*           bcnt    = (int*)alloc(256 * sizeof(int));
    int*           boff    = (int*)alloc(257 * sizeof(int));
    int*           bcur    = (int*)alloc(256 * sizeof(int));
    int*           row_off = (int*)alloc((size_t)(N + 1) * sizeof(int));
    int*           adj     = (int*)alloc((size_t)E * sizeof(int));
    int2*          edge2   = (int2*)alloc((size_t)E * sizeof(int2));
    unsigned char* stA     = (unsigned char*)alloc((size_t)N);
    unsigned char* stB     = (unsigned char*)alloc((size_t)N);
    int*           ambc    = (int*)alloc(RG_ITERS * sizeof(int));
    int*           ambl    = (int*)alloc((size_t)N * sizeof(int));
    float*         table   = (float*)alloc(RG_S * RG_OUT * sizeof(float));

    hipMemsetAsync(bcnt, 0, 256 * sizeof(int), stream);
    hipMemsetAsync(ambc, 0, RG_ITERS * sizeof(int), stream);
    detect_i64_kernel<<<1, 64, 0, stream>>>((const unsigned int*)ei, flag);

    bcount_kernel<<<512, 256, 0, stream>>>(ei, flag, bcnt, E);
    bscan_kernel<<<1, 256, 0, stream>>>(bcnt, boff, bcur, row_off, N);
    part_kernel<<<1024, 256, 0, stream>>>(ei, flag, edge2, bcur, E);
    csr_kernel<<<NB, 256, 0, stream>>>(edge2, boff, row_off, adj, N);

    input_kernel<<<768, 256, 0, stream>>>(x, W_in, b_in, stA, N);

    unsigned char* sin = stA;
    unsigned char* sout = stB;
    for (int it = 0; it < RG_ITERS; ++it) {
        iter_screen_kernel<<<1024, 256, 0, stream>>>(row_off, adj, sin, sout, W_rec, b_rec,
                                                     bn_g, bn_b, bn_m, bn_v,
                                                     ambc + it, ambl, N);
        iter_fix_kernel<<<128, 256, 0, stream>>>(ambc + it, ambl, row_off, adj, sin, sout,
                                                 W_rec, b_rec, bn_g, bn_b, bn_m, bn_v);
        unsigned char* t = sin; sin = sout; sout = t;
    }

    table_kernel<<<1, 64, 0, stream>>>(Wo1, bo1, bno_g, bno_b, bno_m, bno_v, Wo2, bo2, table);
    out_kernel<<<(N + 255) / 256, 256, 0, stream>>>(sin, table, (float*)d_out, N);
}

// Round 17
// 872.301 us; speedup vs baseline: 1.0564x; 1.0062x over previous
//
#include <hip/hip_runtime.h>

#define RG_ITERS 12
#define RG_S 64
#define RG_IN 128
#define RG_H 16
#define RG_OUT 8
#define RG_BN_EPS 1e-5
#define RG_IN_THRESH 2e-3f   // f32 screen gap threshold, input layer (err bound ~1e-5)
#define RG_IT_THRESH 5e-4f   // f32 screen gap threshold, recurrent layer (err bound ~2e-5)

// ---------------------------------------------------------------------------
// Detect whether edge_index buffer is int64 (odd int32 words all zero) or int32
// ---------------------------------------------------------------------------
__global__ void detect_i64_kernel(const unsigned int* __restrict__ ei32, int* __restrict__ flag) {
    if (blockIdx.x == 0 && threadIdx.x == 0) {
        int allz = 1;
        for (int i = 1; i < 64; i += 2) allz &= (ei32[i] == 0u);
        *flag = allz;  // 1 -> int64, 0 -> int32
    }
}

__device__ __forceinline__ int rg_src(const void* ei, int is64, int E, int i) {
    return is64 ? (int)((const long long*)ei)[i] : ((const int*)ei)[i];
}
__device__ __forceinline__ int rg_dst(const void* ei, int is64, int E, int i) {
    return is64 ? (int)((const long long*)ei)[(long long)E + i] : ((const int*)ei)[(long long)E + i];
}

// ---------------------------------------------------------------------------
// Radix-partition CSR build. Bucket = dst>>9 (512 nodes/bucket, NB<=256).
// ---------------------------------------------------------------------------
__global__ __launch_bounds__(256) void bcount_kernel(const void* __restrict__ ei,
                                                     const int* __restrict__ flag,
                                                     int* __restrict__ bcnt, int E) {
    __shared__ int l[256];
    l[threadIdx.x] = 0;
    __syncthreads();
    int is64 = *flag;
    int stride = gridDim.x * 256;
    for (int i = blockIdx.x * 256 + threadIdx.x; i < E; i += stride) {
        int d = rg_dst(ei, is64, E, i);
        atomicAdd(&l[d >> 9], 1);
    }
    __syncthreads();
    if (l[threadIdx.x]) atomicAdd(&bcnt[threadIdx.x], l[threadIdx.x]);
}

__global__ __launch_bounds__(256) void bscan_kernel(const int* __restrict__ bcnt,
                                                    int* __restrict__ boff,
                                                    int* __restrict__ bcur,
                                                    int* __restrict__ row_off, int N) {
    __shared__ int buf[256];
    int t = threadIdx.x;
    int v = bcnt[t];
    buf[t] = v;
    __syncthreads();
    for (int off = 1; off < 256; off <<= 1) {
        int u = (t >= off) ? buf[t - off] : 0;
        __syncthreads();
        buf[t] += u;
        __syncthreads();
    }
    int excl = buf[t] - v;
    boff[t] = excl;
    bcur[t] = excl;
    if (t == 255) {
        boff[256] = buf[t];
        row_off[N] = buf[t];  // total edges
    }
}

__global__ __launch_bounds__(256) void part_kernel(const void* __restrict__ ei,
                                                   const int* __restrict__ flag,
                                                   int2* __restrict__ edge2,
                                                   int* __restrict__ bcur, int E) {
    __shared__ int lcnt[256];
    __shared__ int lbase[256];
    int is64 = *flag;
    int t = threadIdx.x;
    int nchunks = (E + 2047) / 2048;
    for (int c = blockIdx.x; c < nchunks; c += gridDim.x) {
        int base = c * 2048;
        lcnt[t] = 0;
        __syncthreads();
        int s[8], d[8], b[8];
#pragma unroll
        for (int j = 0; j < 8; ++j) {
            int i = base + j * 256 + t;
            if (i < E) {
                s[j] = rg_src(ei, is64, E, i);
                d[j] = rg_dst(ei, is64, E, i);
                b[j] = d[j] >> 9;
                atomicAdd(&lcnt[b[j]], 1);
            } else {
                b[j] = -1;
            }
        }
        __syncthreads();
        int lc = lcnt[t];
        if (lc) lbase[t] = atomicAdd(&bcur[t], lc);
        lcnt[t] = 0;
        __syncthreads();
#pragma unroll
        for (int j = 0; j < 8; ++j) {
            if (b[j] >= 0) {
                int r = atomicAdd(&lcnt[b[j]], 1);
                edge2[lbase[b[j]] + r] = make_int2(s[j], d[j]);
            }
        }
        __syncthreads();  // protect lcnt/lbase before next chunk reuses them
    }
}

__global__ __launch_bounds__(256) void csr_kernel(const int2* __restrict__ edge2,
                                                  const int* __restrict__ boff,
                                                  int* __restrict__ row_off,
                                                  int* __restrict__ adj, int N) {
    __shared__ int cnt[512];
    __shared__ int ps[256];
    int b = blockIdx.x;
    int t = threadIdx.x;
    int lo = b << 9;
    int ebase = boff[b], eend = boff[b + 1];
    cnt[t] = 0;
    cnt[t + 256] = 0;
    __syncthreads();
    for (int i = ebase + t; i < eend; i += 256) {
        int d = edge2[i].y;
        atomicAdd(&cnt[d - lo], 1);
    }
    __syncthreads();
    int c0 = cnt[2 * t], c1 = cnt[2 * t + 1];
    ps[t] = c0 + c1;
    __syncthreads();
    for (int off = 1; off < 256; off <<= 1) {
        int u = (t >= off) ? ps[t - off] : 0;
        __syncthreads();
        ps[t] += u;
        __syncthreads();
    }
    int excl = ps[t] - (c0 + c1);
    cnt[2 * t] = excl;          // becomes cursor
    cnt[2 * t + 1] = excl + c0;
    if (lo + 2 * t < N) row_off[lo + 2 * t] = ebase + excl;
    if (lo + 2 * t + 1 < N) row_off[lo + 2 * t + 1] = ebase + excl + c0;
    __syncthreads();
    for (int i = ebase + t; i < eend; i += 256) {
        int2 e = edge2[i];
        int p = atomicAdd(&cnt[e.y - lo], 1);
        adj[ebase + p] = e.x;  // row order nondeterministic; counting is order-invariant
    }
}

// ---------------------------------------------------------------------------
// Wave top-2 merge butterfly; tie-break smaller index (matches jnp.argmax).
// ---------------------------------------------------------------------------
__device__ __forceinline__ void top2_f32(float y, int lane, float& v1, int& i1, float& v2) {
    v1 = y; i1 = lane; v2 = -3.4e38f;
#pragma unroll
    for (int off = 32; off; off >>= 1) {
        float ov1 = __shfl_xor(v1, off);
        int oi1 = __shfl_xor(i1, off);
        float ov2 = __shfl_xor(v2, off);
        bool take = (ov1 > v1) || (ov1 == v1 && oi1 < i1);
        float nv2 = take ? fmaxf(v1, ov2) : fmaxf(v2, ov1);
        v1 = take ? ov1 : v1;
        i1 = take ? oi1 : i1;
        v2 = nv2;
    }
}

__device__ __forceinline__ int argmax_f64(double y, int lane) {
    double best = y;
    int bi = lane;
#pragma unroll
    for (int off = 32; off; off >>= 1) {
        double ov = __shfl_xor(best, off);
        int oi = __shfl_xor(bi, off);
        if (ov > best || (ov == best && oi < bi)) { best = ov; bi = oi; }
    }
    return bi;
}

// ---------------------------------------------------------------------------
// Full-wave ballot histogram (cold path): cnt = #in-neighbors state==lane, <=10
// ---------------------------------------------------------------------------
__device__ __forceinline__ int hist_count(const int* __restrict__ adj,
                                          const unsigned char* __restrict__ st_in,
                                          int beg, int end, int lane) {
    int cnt = 0;
    for (int base = beg; base < end; base += 64) {
        int idx = base + lane;
        unsigned long long valid = __ballot(idx < end);
        int sv = (idx < end) ? (int)st_in[adj[idx]] : 0;
        unsigned long long mm = valid;
#pragma unroll
        for (int b = 0; b < 6; ++b) {
            unsigned long long bl = __ballot(((sv >> b) & 1) != 0);
            mm &= ((lane >> b) & 1) ? bl : ~bl;
        }
        cnt += (int)__popcll(mm);
    }
    return cnt > 10 ? 10 : cnt;
}

// Byte butterfly pack (cold path only): count -> pk[16] bytes
__device__ __forceinline__ void pack_bytes(unsigned cmin, int lane, unsigned pk[16]) {
    unsigned v = cmin, p;
    p = __shfl_xor(v, 1); v = (lane & 1) ? (p | (v << 8)) : (v | (p << 8));
    p = __shfl_xor(v, 2); v = (lane & 2) ? (p | (v << 16)) : (v | (p << 16));
    unsigned q0, q1;
    p = __shfl_xor(v, 4); q0 = (lane & 4) ? p : v; q1 = (lane & 4) ? v : p;
    unsigned r0 = __shfl_xor(q0, 8), r1 = __shfl_xor(q1, 8);
    unsigned u0, u1, u2, u3;
    if (lane & 8) { u0 = r0; u1 = r1; u2 = q0; u3 = q1; }
    else          { u0 = q0; u1 = q1; u2 = r0; u3 = r1; }
    unsigned w0 = __shfl_xor(u0, 16), w1 = __shfl_xor(u1, 16),
             w2 = __shfl_xor(u2, 16), w3 = __shfl_xor(u3, 16);
    unsigned a0, a1, a2, a3, a4, a5, a6, a7;
    if (lane & 16) { a0 = w0; a1 = w1; a2 = w2; a3 = w3; a4 = u0; a5 = u1; a6 = u2; a7 = u3; }
    else           { a0 = u0; a1 = u1; a2 = u2; a3 = u3; a4 = w0; a5 = w1; a6 = w2; a7 = w3; }
    unsigned b0 = __shfl_xor(a0, 32), b1 = __shfl_xor(a1, 32), b2 = __shfl_xor(a2, 32),
             b3 = __shfl_xor(a3, 32), b4 = __shfl_xor(a4, 32), b5 = __shfl_xor(a5, 32),
             b6 = __shfl_xor(a6, 32), b7 = __shfl_xor(a7, 32);
    if (lane & 32) {
        pk[0] = b0; pk[1] = b1; pk[2] = b2; pk[3] = b3;
        pk[4] = b4; pk[5] = b5; pk[6] = b6; pk[7] = b7;
        pk[8] = a0; pk[9] = a1; pk[10] = a2; pk[11] = a3;
        pk[12] = a4; pk[13] = a5; pk[14] = a6; pk[15] = a7;
    } else {
        pk[0] = a0; pk[1] = a1; pk[2] = a2; pk[3] = a3;
        pk[4] = a4; pk[5] = a5; pk[6] = a6; pk[7] = a7;
        pk[8] = b0; pk[9] = b1; pk[10] = b2; pk[11] = b3;
        pk[12] = b4; pk[13] = b5; pk[14] = b6; pk[15] = b7;
    }
}

// ---------------------------------------------------------------------------
// Input layer: LDS-staged, software-pipelined (round-10 version).
// ---------------------------------------------------------------------------
__device__ __forceinline__ int input_f64_node(const float4* __restrict__ xr,
                                              const float* __restrict__ wsh,
                                              double bind, int lane) {
    double a0 = 0.0, a1 = 0.0, a2 = 0.0, a3 = 0.0;
#pragma unroll 8
    for (int k4 = 0; k4 < RG_IN / 4; ++k4) {
        float4 xv = xr[k4];
        int k = k4 * 4;
        a0 += (double)xv.x * (double)wsh[(k + 0) * RG_S + lane];
        a1 += (double)xv.y * (double)wsh[(k + 1) * RG_S + lane];
        a2 += (double)xv.z * (double)wsh[(k + 2) * RG_S + lane];
        a3 += (double)xv.w * (double)wsh[(k + 3) * RG_S + lane];
    }
    double acc = bind + ((a0 + a2) + (a1 + a3));
    return argmax_f64(acc, lane);
}

__global__ __launch_bounds__(256) void input_kernel(const float* __restrict__ x,
                                                    const float* __restrict__ W_in,
                                                    const float* __restrict__ b_in,
                                                    unsigned char* __restrict__ st, int n) {
    __shared__ float wsh[RG_IN * RG_S];   // 32 KB
    __shared__ float xs[4][8 * RG_IN];    // 16 KB: per-wave 8-row x buffer
    for (int i = threadIdx.x; i < RG_IN * RG_S; i += 256) wsh[i] = W_in[i];
    __syncthreads();
    int lane = threadIdx.x & 63;
    int wid = threadIdx.x >> 6;
    float binf = b_in[lane];
    double bind = (double)binf;
    float* myxs = xs[wid];
    int wave = blockIdx.x * 4 + wid;
    int nwaves = gridDim.x * 4;
    int nfull = n >> 3;

    if (wave < nfull) {
        int g = wave;
        float4 xr[4];
        {
            const float4* gp = (const float4*)(x + (size_t)g * 8 * RG_IN);
#pragma unroll
            for (int j = 0; j < 4; ++j) xr[j] = gp[lane + 64 * j];
        }
        while (true) {
#pragma unroll
            for (int j = 0; j < 4; ++j) ((float4*)myxs)[lane + 64 * j] = xr[j];
            int base = g * 8;
            int gn = g + nwaves;
            bool hasNext = gn < nfull;
            if (hasNext) {
                const float4* gp = (const float4*)(x + (size_t)gn * 8 * RG_IN);
#pragma unroll
                for (int j = 0; j < 4; ++j) xr[j] = gp[lane + 64 * j];
            }
            float acc[8][4];
#pragma unroll
            for (int j = 0; j < 8; ++j)
#pragma unroll
                for (int c = 0; c < 4; ++c) acc[j][c] = 0.f;
#pragma unroll 2
            for (int k4 = 0; k4 < RG_IN / 4; ++k4) {
                int k = k4 * 4;
                float w0 = wsh[(k + 0) * RG_S + lane];
                float w1 = wsh[(k + 1) * RG_S + lane];
                float w2 = wsh[(k + 2) * RG_S + lane];
                float w3 = wsh[(k + 3) * RG_S + lane];
#pragma unroll
                for (int j = 0; j < 8; ++j) {
                    float4 v = *(const float4*)&myxs[j * RG_IN + k4 * 4];
                    acc[j][0] += v.x * w0;
                    acc[j][1] += v.y * w1;
                    acc[j][2] += v.z * w2;
                    acc[j][3] += v.w * w3;
                }
            }
            int sres[8];
#pragma unroll
            for (int j = 0; j < 8; ++j) {
                float y = ((acc[j][0] + acc[j][2]) + (acc[j][1] + acc[j][3])) + binf;
                float v1f, v2f;
                int i1;
                top2_f32(y, lane, v1f, i1, v2f);
                sres[j] = (v1f - v2f < RG_IN_THRESH)
                              ? input_f64_node((const float4*)(x + (size_t)(base + j) * RG_IN),
                                               wsh, bind, lane)
                              : i1;
            }
            if (lane == 0) {
#pragma unroll
                for (int j = 0; j < 8; ++j) st[base + j] = (unsigned char)sres[j];
            }
            if (!hasNext) break;
            g = gn;
        }
    }
    for (int node = nfull * 8 + wave; node < n; node += nwaves) {
        const float4* xr4 = (const float4*)(x + (size_t)node * RG_IN);
        float f0 = 0.f, f1 = 0.f, f2 = 0.f, f3 = 0.f;
#pragma unroll 4
        for (int k4 = 0; k4 < RG_IN / 4; ++k4) {
            float4 xv = xr4[k4];
            int k = k4 * 4;
            f0 += xv.x * wsh[(k + 0) * RG_S + lane];
            f1 += xv.y * wsh[(k + 1) * RG_S + lane];
            f2 += xv.z * wsh[(k + 2) * RG_S + lane];
            f3 += xv.w * wsh[(k + 3) * RG_S + lane];
        }
        float y = ((f0 + f2) + (f1 + f3)) + binf;
        float v1f, v2f;
        int i1;
        top2_f32(y, lane, v1f, i1, v2f);
        int sres = (v1f - v2f < RG_IN_THRESH) ? input_f64_node(xr4, wsh, bind, lane) : i1;
        if (lane == 0) st[node] = (unsigned char)sres;
    }
}

// ---------------------------------------------------------------------------
// Recurrent iteration, phase 1 (hot): round-8/10 proven body, with T1
// XCD-aware node partition: XCD r = blockIdx%8 owns contiguous node range
// [r*span, (r+1)*span) so its adj slice (~E/8 = 1.6MB) stays resident in
// that XCD's 4MB L2 across all 12 iterations (adj is read-only). Coverage
// is bijective: wave-local offset wxcd in [0,512) covers o%1024 in [0,512)
// as nA and [512,1024) as its nB=nA+512 partner. Math per node unchanged.
// ---------------------------------------------------------------------------
__global__ __launch_bounds__(256) void iter_screen_kernel(
    const int* __restrict__ row_off, const int* __restrict__ adj,
    const unsigned char* __restrict__ st_in, unsigned char* __restrict__ st_out,
    const float* __restrict__ W_rec, const float* __restrict__ b_rec,
    const float* __restrict__ bn_g, const float* __restrict__ bn_b,
    const float* __restrict__ bn_m, const float* __restrict__ bn_v,
    int* __restrict__ amb_cnt, int* __restrict__ amb_list, int n) {
    __shared__ unsigned int cslot[4][2][16];  // [wave][node A/B][64 byte counts]
    int lane = threadIdx.x & 63;
    int wid = threadIdx.x >> 6;
    int sub = lane & 31;
    bool hiHalf = lane >= 32;

    float s = bn_g[lane] * rsqrtf(bn_v[lane] + 1e-5f);
    float biasp = b_rec[lane] * s + (bn_b[lane] - bn_m[lane] * s);
    float wcol[RG_S];
#pragma unroll
    for (int k = 0; k < RG_S; ++k) wcol[k] = W_rec[k * RG_S + lane] * s;

    unsigned char* slotA = (unsigned char*)&cslot[wid][0][0];
    unsigned char* slotB = (unsigned char*)&cslot[wid][1][0];

    // T1 partition (grid must be a multiple of 8; 1024 here)
    int xcd = blockIdx.x & 7;
    int nbx = gridDim.x >> 3;            // blocks per XCD
    int bloc = blockIdx.x >> 3;          // block index within XCD
    int span = (n + 7) >> 3;
    int lo = xcd * span;
    int hi = lo + span; if (hi > n) hi = n;
    int wxcd = bloc * 4 + wid;           // wave index within XCD
    int wlocal = nbx * 4;                // waves per XCD

    for (int nA = lo + wxcd; nA < hi; nA += 2 * wlocal) {
        int nB = nA + wlocal;
        bool hasB = nB < hi;
        int nBc = hasB ? nB : nA;
        int begA = row_off[nA], endA = row_off[nA + 1];
        int begB = row_off[nBc], endB = row_off[nBc + 1];
        int stoA = (int)st_in[nA];
        int stoB = (int)st_in[nBc];
        float wselfA = W_rec[(RG_S + stoA) * RG_S + lane] * s;
        float wselfB = W_rec[(RG_S + stoB) * RG_S + lane] * s;

        int myBeg = hiHalf ? begB : begA;
        int myDeg = hiHalf ? (endB - begB) : (endA - begA);
        int dA = endA - begA, dB = endB - begB;
        int dmax = dA > dB ? dA : dB;
        int cntA = 0, cntB = 0;
        for (int base = 0; base < dmax; base += 32) {
            int off = base + sub;
            bool v = off < myDeg;
            unsigned long long valid = __ballot(v);
            int sv = v ? (int)st_in[adj[myBeg + off]] : 0;
            unsigned long long mm = valid;
#pragma unroll
            for (int b = 0; b < 6; ++b) {
                unsigned long long bl = __ballot(((sv >> b) & 1) != 0);
                mm &= ((lane >> b) & 1) ? bl : ~bl;
            }
            cntA += (int)__popcll(mm & 0xFFFFFFFFull);
            cntB += (int)__popcll(mm >> 32);
        }
        slotA[lane] = (unsigned char)(cntA > 10 ? 10 : cntA);
        slotB[lane] = (unsigned char)(cntB > 10 ? 10 : cntB);

        // same-wave DS ordering: all lanes' byte writes precede these reads
        float yA0 = 0.f, yA1 = 0.f, yA2 = 0.f, yA3 = 0.f;
        float yB0 = 0.f, yB1 = 0.f, yB2 = 0.f, yB3 = 0.f;
#pragma unroll
        for (int g = 0; g < 16; ++g) {
            unsigned pA = cslot[wid][0][g];
            unsigned pB = cslot[wid][1][g];
            yA0 += (float)(pA & 0xFFu)         * wcol[4 * g + 0];
            yA1 += (float)((pA >> 8) & 0xFFu)  * wcol[4 * g + 1];
            yA2 += (float)((pA >> 16) & 0xFFu) * wcol[4 * g + 2];
            yA3 += (float)(pA >> 24)           * wcol[4 * g + 3];
            yB0 += (float)(pB & 0xFFu)         * wcol[4 * g + 0];
            yB1 += (float)((pB >> 8) & 0xFFu)  * wcol[4 * g + 1];
            yB2 += (float)((pB >> 16) & 0xFFu) * wcol[4 * g + 2];
            yB3 += (float)(pB >> 24)           * wcol[4 * g + 3];
        }
        float yA = ((yA0 + yA2) + (yA1 + yA3)) + biasp + wselfA;
        float v1, v2;
        int i1;
        top2_f32(yA, lane, v1, i1, v2);
        if (lane == 0) {
            st_out[nA] = (unsigned char)i1;
            if (v1 - v2 < RG_IT_THRESH) {
                int pidx = atomicAdd(amb_cnt, 1);
                amb_list[pidx] = nA;
            }
        }
        if (hasB) {
            float yB = ((yB0 + yB2) + (yB1 + yB3)) + biasp + wselfB;
            top2_f32(yB, lane, v1, i1, v2);
            if (lane == 0) {
                st_out[nB] = (unsigned char)i1;
                if (v1 - v2 < RG_IT_THRESH) {
                    int pidx = atomicAdd(amb_cnt, 1);
                    amb_list[pidx] = nB;
                }
            }
        }
    }
}

// ---------------------------------------------------------------------------
// Recurrent iteration, phase 2 (rare): exact f64 recompute for listed nodes.
// ---------------------------------------------------------------------------
__global__ __launch_bounds__(256) void iter_fix_kernel(
    const int* __restrict__ amb_cnt, const int* __restrict__ amb_list,
    const int* __restrict__ row_off, const int* __restrict__ adj,
    const unsigned char* __restrict__ st_in, unsigned char* __restrict__ st_out,
    const float* __restrict__ W_rec, const float* __restrict__ b_rec,
    const float* __restrict__ bn_g, const float* __restrict__ bn_b,
    const float* __restrict__ bn_m, const float* __restrict__ bn_v) {
    int tot = *amb_cnt;
    if (tot <= 0) return;
    int lane = threadIdx.x & 63;
    int wid = threadIdx.x >> 6;
    double brec = (double)b_rec[lane];
    double bnm = (double)bn_m[lane];
    double bns = (double)bn_g[lane] / sqrt((double)bn_v[lane] + RG_BN_EPS);
    double bnb = (double)bn_b[lane];
    int nw = gridDim.x * 4;
    for (int li = blockIdx.x * 4 + wid; li < tot; li += nw) {
        int node = amb_list[li];
        int beg = row_off[node], end = row_off[node + 1];
        int st_old = (int)st_in[node];
        float wself = W_rec[(RG_S + st_old) * RG_S + lane];
        int cmin = hist_count(adj, st_in, beg, end, lane);
        unsigned pk[16];
        pack_bytes((unsigned)cmin, lane, pk);
        double z0 = 0.0, z1 = 0.0, z2 = 0.0, z3 = 0.0;
#pragma unroll
        for (int g = 0; g < 16; ++g) {
            unsigned pg = pk[g];
            z0 += (double)(pg & 0xFFu)         * (double)W_rec[(4 * g + 0) * RG_S + lane];
            z1 += (double)((pg >> 8) & 0xFFu)  * (double)W_rec[(4 * g + 1) * RG_S + lane];
            z2 += (double)((pg >> 16) & 0xFFu) * (double)W_rec[(4 * g + 2) * RG_S + lane];
            z3 += (double)(pg >> 24)           * (double)W_rec[(4 * g + 3) * RG_S + lane];
        }
        double z = ((z0 + z2) + (z1 + z3)) + brec + (double)wself;
        double y = (z - bnm) * bns + bnb;
        int st_res = argmax_f64(y, lane);
        if (lane == 0) st_out[node] = (unsigned char)st_res;
    }
}

// ---------------------------------------------------------------------------
// Output MLP collapses to a 64x8 lookup table over the final state
// ---------------------------------------------------------------------------
__global__ void table_kernel(const float* __restrict__ Wo1, const float* __restrict__ bo1,
                             const float* __restrict__ g, const float* __restrict__ b,
                             const float* __restrict__ m, const float* __restrict__ v,
                             const float* __restrict__ Wo2, const float* __restrict__ bo2,
                             float* __restrict__ table) {
    int k = threadIdx.x;
    if (k >= RG_S) return;
    double h[RG_H];
#pragma unroll
    for (int j = 0; j < RG_H; ++j) {
        double z = (double)Wo1[k * RG_H + j] + (double)bo1[j];
        double y = (z - (double)m[j]) * ((double)g[j] / sqrt((double)v[j] + RG_BN_EPS)) +
                   (double)b[j];
        h[j] = y > 0.0 ? y : 0.0;
    }
#pragma unroll
    for (int o = 0; o < RG_OUT; ++o) {
        double acc = (double)bo2[o];
#pragma unroll
        for (int j = 0; j < RG_H; ++j) acc += h[j] * (double)Wo2[j * RG_OUT + o];
        table[k * RG_OUT + o] = (float)acc;
    }
}

__global__ void out_kernel(const unsigned char* __restrict__ st, const float* __restrict__ table,
                           float* __restrict__ out, int n) {
    int i = blockIdx.x * blockDim.x + threadIdx.x;
    if (i >= n) return;
    int s = (int)st[i];
    float4 a = ((const float4*)table)[s * 2];
    float4 b = ((const float4*)table)[s * 2 + 1];
    ((float4*)out)[(size_t)i * 2] = a;
    ((float4*)out)[(size_t)i * 2 + 1] = b;
}

// ---------------------------------------------------------------------------
extern "C" void kernel_launch(void* const* d_in, const int* in_sizes, int n_in,
                              void* d_out, int out_size, void* d_ws, size_t ws_size,
                              hipStream_t stream) {
    const float* x     = (const float*)d_in[0];
    const void*  ei    = d_in[1];
    const float* W_in  = (const float*)d_in[2];
    const float* b_in  = (const float*)d_in[3];
    const float* W_rec = (const float*)d_in[4];
    const float* b_rec = (const float*)d_in[5];
    const float* bn_g  = (const float*)d_in[6];
    const float* bn_b  = (const float*)d_in[7];
    const float* bn_m  = (const float*)d_in[8];
    const float* bn_v  = (const float*)d_in[9];
    const float* Wo1   = (const float*)d_in[10];
    const float* bo1   = (const float*)d_in[11];
    const float* bno_g = (const float*)d_in[12];
    const float* bno_b = (const float*)d_in[13];
    const float* bno_m = (const float*)d_in[14];
    const float* bno_v = (const float*)d_in[15];
    const float* Wo2   = (const float*)d_in[16];
    const float* bo2   = (const float*)d_in[17];

    int N = in_sizes[0] / RG_IN;
    int E = in_sizes[1] / 2;
    int NB = (N + 511) >> 9;  // buckets of 512 nodes; <=256 for N<=131072

    char* ws = (char*)d_ws;
    size_t off = 0;
    auto alloc = [&](size_t bytes) -> void* {
        void* p = ws + off;
        off = (off + bytes + 255) & ~(size_t)255;
        return p;
    };
    int*           flag    = (int*)alloc(sizeof(int));
    int*           bcnt    = (int*)alloc(256 * sizeof(int));
    int*           boff    = (int*)alloc(257 * sizeof(int));
    int*           bcur    = (int*)alloc(256 * sizeof(int));
    int*           row_off = (int*)alloc((size_t)(N + 1) * sizeof(int));
    int*           adj     = (int*)alloc((size_t)E * sizeof(int));
    int2*          edge2   = (int2*)alloc((size_t)E * sizeof(int2));
    unsigned char* stA     = (unsigned char*)alloc((size_t)N);
    unsigned char* stB     = (unsigned char*)alloc((size_t)N);
    int*           ambc    = (int*)alloc(RG_ITERS * sizeof(int));
    int*           ambl    = (int*)alloc((size_t)N * sizeof(int));
    float*         table   = (float*)alloc(RG_S * RG_OUT * sizeof(float));

    hipMemsetAsync(bcnt, 0, 256 * sizeof(int), stream);
    hipMemsetAsync(ambc, 0, RG_ITERS * sizeof(int), stream);
    detect_i64_kernel<<<1, 64, 0, stream>>>((const unsigned int*)ei, flag);

    bcount_kernel<<<512, 256, 0, stream>>>(ei, flag, bcnt, E);
    bscan_kernel<<<1, 256, 0, stream>>>(bcnt, boff, bcur, row_off, N);
    part_kernel<<<1024, 256, 0, stream>>>(ei, flag, edge2, bcur, E);
    csr_kernel<<<NB, 256, 0, stream>>>(edge2, boff, row_off, adj, N);

    input_kernel<<<768, 256, 0, stream>>>(x, W_in, b_in, stA, N);

    unsigned char* sin = stA;
    unsigned char* sout = stB;
    for (int it = 0; it < RG_ITERS; ++it) {
        iter_screen_kernel<<<1024, 256, 0, stream>>>(row_off, adj, sin, sout, W_rec, b_rec,
                                                     bn_g, bn_b, bn_m, bn_v,
                                                     ambc + it, ambl, N);
        iter_fix_kernel<<<128, 256, 0, stream>>>(ambc + it, ambl, row_off, adj, sin, sout,
                                                 W_rec, b_rec, bn_g, bn_b, bn_m, bn_v);
        unsigned char* t = sin; sin = sout; sout = t;
    }

    table_kernel<<<1, 64, 0, stream>>>(Wo1, bo1, bno_g, bno_b, bno_m, bno_v, Wo2, bo2, table);
    out_kernel<<<(N + 255) / 256, 256, 0, stream>>>(sin, table, (float*)d_out, N);
}